// Round 2
// baseline (567.091 us; speedup 1.0000x reference)
//
#include <hip/hip_runtime.h>

// Sizes (fixed by the problem)
#define BATCH 4
#define TSEQ  2048
#define UNITS 1024
#define HEADS 8
#define DH    128
#define MROWS (BATCH*TSEQ)          // 8192
#define NCAT  (2*UNITS + DH)        // 2176

typedef short bf16x8 __attribute__((ext_vector_type(8)));
typedef float f32x4  __attribute__((ext_vector_type(4)));

__device__ __forceinline__ short f2bf(float f){
    union { float f; unsigned u; } v; v.f = f;
    unsigned r = v.u + 0x7fff + ((v.u >> 16) & 1);
    return (short)(r >> 16);
}
__device__ __forceinline__ float bf2f(short s){
    union { unsigned u; float f; } v; v.u = ((unsigned)(unsigned short)s) << 16;
    return v.f;
}
__device__ __forceinline__ float redmax16(float v){
    #pragma unroll
    for (int m = 1; m < 16; m <<= 1) v = fmaxf(v, __shfl_xor(v, m));
    return v;
}
__device__ __forceinline__ float redsum16(float v){
    #pragma unroll
    for (int m = 1; m < 16; m <<= 1) v += __shfl_xor(v, m);
    return v;
}

// ---------------------------------------------------------------------------
// Pack: x -> bf16; WT[n][k] = concat(Wq*scale | Wk | Wv) transposed, bf16;
//       WoT[n][k] = Wo^T bf16.
// ---------------------------------------------------------------------------
__global__ void pack_kernel(const float* __restrict__ x,
                            const float* __restrict__ Wq,
                            const float* __restrict__ Wk,
                            const float* __restrict__ Wv,
                            const float* __restrict__ Wo,
                            short* __restrict__ Xbf,
                            short* __restrict__ WT,
                            short* __restrict__ WoT)
{
    const float scale = 0.08838834764831845f; // 1/sqrt(128)
    const int NX = MROWS*UNITS;               // 8388608
    const int NW = NCAT*UNITS;                // 2228224
    const int NO = UNITS*DH;                  // 131072
    const int total = NX + NW + NO;
    for (int i = blockIdx.x*256 + threadIdx.x; i < total; i += gridDim.x*256){
        if (i < NX){
            Xbf[i] = f2bf(x[i]);
        } else if (i < NX + NW){
            int j = i - NX;
            int n = j >> 10, k = j & 1023;
            float v;
            if (n < UNITS)        v = Wq[k*UNITS + n] * scale;
            else if (n < 2*UNITS) v = Wk[k*UNITS + (n - UNITS)];
            else                  v = Wv[k*DH + (n - 2*UNITS)];
            WT[n*UNITS + k] = f2bf(v);
        } else {
            int j = i - NX - NW;
            int n = j >> 7, dd = j & 127;
            WoT[n*DH + dd] = f2bf(Wo[dd*UNITS + n]);
        }
    }
}

// ---------------------------------------------------------------------------
// QKV GEMM: X[8192,1024]bf16 @ WT^T -> scatter Q,K [B,H,T,d] (Q pre-scaled),
// V^T [B,d,T]. 128x128 tile, BK=32, 4 waves (2x2), 16x16x32 MFMA.
// ---------------------------------------------------------------------------
__global__ __launch_bounds__(256) void gemm_qkv_kernel(
    const short* __restrict__ X, const short* __restrict__ WT,
    short* __restrict__ Qbf, short* __restrict__ Kbf, short* __restrict__ Vt)
{
    __shared__ short A_lds[128][40];
    __shared__ short B_lds[128][40];
    const int tid = threadIdx.x;
    const int w = tid >> 6, l = tid & 63, lg = l >> 4, lr = l & 15;
    const int wm = w >> 1, wn = w & 1;
    const int n0 = blockIdx.x * 128;
    const int m0 = blockIdx.y * 128;
    const f32x4 fzero = {0.f, 0.f, 0.f, 0.f};
    f32x4 acc[4][4];
    #pragma unroll
    for (int i = 0; i < 4; i++)
        #pragma unroll
        for (int j = 0; j < 4; j++) acc[i][j] = fzero;

    for (int k0 = 0; k0 < UNITS; k0 += 32){
        #pragma unroll
        for (int i = 0; i < 2; i++){
            int c = tid + i*256;                 // 512 chunks of 16B
            int row = c >> 2, c8 = c & 3;
            *(bf16x8*)(&A_lds[row][c8*8]) =
                *(const bf16x8*)(X + (size_t)(m0+row)*UNITS + k0 + c8*8);
            *(bf16x8*)(&B_lds[row][c8*8]) =
                *(const bf16x8*)(WT + (size_t)(n0+row)*UNITS + k0 + c8*8);
        }
        __syncthreads();
        bf16x8 af[4], bfr[4];
        #pragma unroll
        for (int mf = 0; mf < 4; mf++)
            af[mf] = *(const bf16x8*)(&A_lds[wm*64 + mf*16 + lr][lg*8]);
        #pragma unroll
        for (int nf = 0; nf < 4; nf++)
            bfr[nf] = *(const bf16x8*)(&B_lds[wn*64 + nf*16 + lr][lg*8]);
        #pragma unroll
        for (int mf = 0; mf < 4; mf++)
            #pragma unroll
            for (int nf = 0; nf < 4; nf++)
                acc[mf][nf] = __builtin_amdgcn_mfma_f32_16x16x32_bf16(
                    af[mf], bfr[nf], acc[mf][nf], 0, 0, 0);
        __syncthreads();
    }

    #pragma unroll
    for (int mf = 0; mf < 4; mf++){
        #pragma unroll
        for (int nf = 0; nf < 4; nf++){
            #pragma unroll
            for (int r = 0; r < 4; r++){
                int gr = m0 + wm*64 + mf*16 + lg*4 + r;
                int gc = n0 + wn*64 + nf*16 + lr;
                int b = gr >> 11, t = gr & 2047;
                short v = f2bf(acc[mf][nf][r]);
                if (gc < UNITS){
                    int h = gc >> 7, dd = gc & 127;
                    Qbf[(((size_t)(b*HEADS + h))*TSEQ + t)*DH + dd] = v;
                } else if (gc < 2*UNITS){
                    int h = (gc - UNITS) >> 7, dd = gc & 127;
                    Kbf[(((size_t)(b*HEADS + h))*TSEQ + t)*DH + dd] = v;
                } else {
                    int dd = gc - 2*UNITS;
                    Vt[((size_t)b*DH + dd)*TSEQ + t] = v;
                }
            }
        }
    }
}

// ---------------------------------------------------------------------------
// Flash O pass: per (b,h,q-tile of 64). 4 waves x 16 q-rows. KVBLK=32.
// Produces Obuf [B,H,T,d] bf16 (already /l) and M (row max), Linv (1/l).
// ---------------------------------------------------------------------------
__global__ __launch_bounds__(256) void flash_o_kernel(
    const short* __restrict__ Qbf, const short* __restrict__ Kbf,
    const short* __restrict__ Vt, short* __restrict__ Obuf,
    float* __restrict__ Mb, float* __restrict__ Lb)
{
    __shared__ short K_lds[32][136];
    __shared__ short V_lds[128][40];
    __shared__ short P_lds[4][16][40];
    const int tid = threadIdx.x;
    const int w = tid >> 6, l = tid & 63, lg = l >> 4, lr = l & 15;
    const int bh = blockIdx.y;                 // b*8+h
    const int b  = bh >> 3;
    const int qt = gridDim.x - 1 - blockIdx.x; // heavy tiles first
    const int q0 = qt * 64;
    const short* Qh = Qbf + (size_t)bh * TSEQ * DH;
    const short* Kh = Kbf + (size_t)bh * TSEQ * DH;
    const short* Vb = Vt  + (size_t)b  * DH * TSEQ;
    const f32x4 fzero = {0.f, 0.f, 0.f, 0.f};

    // Q fragments in registers (A layout: row = l&15, k-chunk = l>>4)
    const int qrow = q0 + w*16 + lr;
    bf16x8 aq[4];
    #pragma unroll
    for (int ks = 0; ks < 4; ks++)
        aq[ks] = *(const bf16x8*)(Qh + (size_t)qrow*DH + ks*32 + lg*8);

    f32x4 oacc[8];
    #pragma unroll
    for (int i = 0; i < 8; i++) oacc[i] = fzero;
    float mrow[4], lrow[4];
    #pragma unroll
    for (int r = 0; r < 4; r++){ mrow[r] = -3.0e38f; lrow[r] = 0.f; }

    const int ntile = (q0 + 64) / 32;
    for (int kt = 0; kt < ntile; kt++){
        const int kv0 = kt * 32;
        #pragma unroll
        for (int i = 0; i < 2; i++){
            int c = tid + i*256;
            int row = c >> 4, c8 = c & 15;
            *(bf16x8*)(&K_lds[row][c8*8]) =
                *(const bf16x8*)(Kh + (size_t)(kv0+row)*DH + c8*8);
        }
        #pragma unroll
        for (int i = 0; i < 2; i++){
            int c = tid + i*256;
            int dd = c >> 2, c8 = c & 3;
            *(bf16x8*)(&V_lds[dd][c8*8]) =
                *(const bf16x8*)(Vb + (size_t)dd*TSEQ + kv0 + c8*8);
        }
        __syncthreads();

        f32x4 sacc[2]; sacc[0] = fzero; sacc[1] = fzero;
        #pragma unroll
        for (int ks = 0; ks < 4; ks++){
            bf16x8 b0 = *(const bf16x8*)(&K_lds[lr][ks*32 + lg*8]);
            bf16x8 b1 = *(const bf16x8*)(&K_lds[16 + lr][ks*32 + lg*8]);
            sacc[0] = __builtin_amdgcn_mfma_f32_16x16x32_bf16(aq[ks], b0, sacc[0], 0,0,0);
            sacc[1] = __builtin_amdgcn_mfma_f32_16x16x32_bf16(aq[ks], b1, sacc[1], 0,0,0);
        }

        // online softmax; D layout: row = lg*4+r, col = lr
        float pm[2][4];
        #pragma unroll
        for (int r = 0; r < 4; r++){
            int qg = q0 + w*16 + lg*4 + r;
            float s0 = sacc[0][r], s1 = sacc[1][r];
            if (kv0 + lr      > qg) s0 = -1e30f;
            if (kv0 + 16 + lr > qg) s1 = -1e30f;
            pm[0][r] = s0; pm[1][r] = s1;
            float rmax = redmax16(fmaxf(s0, s1));
            float mnew = fmaxf(mrow[r], rmax);
            float sf = __expf(mrow[r] - mnew);
            mrow[r] = mnew;
            float p0 = __expf(pm[0][r] - mnew);
            float p1 = __expf(pm[1][r] - mnew);
            pm[0][r] = p0; pm[1][r] = p1;
            lrow[r] = lrow[r]*sf + redsum16(p0 + p1);
            #pragma unroll
            for (int cg = 0; cg < 8; cg++) oacc[cg][r] *= sf;
        }

        // transpose P via per-wave LDS bounce into A layout
        #pragma unroll
        for (int r = 0; r < 4; r++){
            P_lds[w][lg*4 + r][lr]      = f2bf(pm[0][r]);
            P_lds[w][lg*4 + r][16 + lr] = f2bf(pm[1][r]);
        }
        bf16x8 pa = *(const bf16x8*)(&P_lds[w][lr][lg*8]);
        #pragma unroll
        for (int cg = 0; cg < 8; cg++){
            bf16x8 bv = *(const bf16x8*)(&V_lds[cg*16 + lr][lg*8]);
            oacc[cg] = __builtin_amdgcn_mfma_f32_16x16x32_bf16(pa, bv, oacc[cg], 0,0,0);
        }
        __syncthreads();
    }

    float rl[4];
    #pragma unroll
    for (int r = 0; r < 4; r++) rl[r] = 1.0f / lrow[r];
    #pragma unroll
    for (int cg = 0; cg < 8; cg++){
        #pragma unroll
        for (int r = 0; r < 4; r++){
            int t = q0 + w*16 + lg*4 + r;
            Obuf[((size_t)bh*TSEQ + t)*DH + cg*16 + lr] = f2bf(oacc[cg][r] * rl[r]);
        }
    }
    if (lr == 0){
        #pragma unroll
        for (int r = 0; r < 4; r++){
            int t = q0 + w*16 + lg*4 + r;
            Mb[(size_t)bh*TSEQ + t] = mrow[r];
            Lb[(size_t)bh*TSEQ + t] = rl[r];
        }
    }
}

// ---------------------------------------------------------------------------
// Head-mean of O -> Abar bf16 [8192,128]
// ---------------------------------------------------------------------------
__global__ void mean_kernel(const short* __restrict__ Obuf, short* __restrict__ Abar)
{
    int e = blockIdx.x*256 + threadIdx.x;
    if (e >= MROWS*DH) return;
    int bt = e >> 7, dd = e & 127;
    int b = bt >> 11, t = bt & 2047;
    float s = 0.f;
    #pragma unroll
    for (int h = 0; h < HEADS; h++)
        s += bf2f(Obuf[(((size_t)(b*HEADS + h))*TSEQ + t)*DH + dd]);
    Abar[e] = f2bf(s * 0.125f);
}

// ---------------------------------------------------------------------------
// attn weights: per (b, lower-tri 64x64 tile pair), loop 8 heads,
// w = exp(S - M)*Linv accumulated, write mean/8. Uses precomputed M/Linv.
// ---------------------------------------------------------------------------
__global__ __launch_bounds__(256) void attn_kernel(
    const short* __restrict__ Qbf, const short* __restrict__ Kbf,
    const float* __restrict__ Mb, const float* __restrict__ Lb,
    float* __restrict__ attn)
{
    __shared__ short Q_lds[64][136];
    __shared__ short K_lds2[64][136];
    const int tid = threadIdx.x;
    const int w = tid >> 6, l = tid & 63, lg = l >> 4, lr = l & 15;
    const int b = blockIdx.y;
    const int p = blockIdx.x;
    int qt = (int)((sqrtf(8.0f*p + 1.0f) - 1.0f) * 0.5f);
    while ((qt+1)*(qt+2)/2 <= p) qt++;
    while (qt*(qt+1)/2 > p) qt--;
    const int kt = p - qt*(qt+1)/2;
    const int q0 = qt*64, k0 = kt*64;
    const f32x4 fzero = {0.f, 0.f, 0.f, 0.f};

    float wacc[4][4] = {};
    for (int h = 0; h < HEADS; h++){
        const short* Qh = Qbf + ((size_t)(b*HEADS + h))*TSEQ*DH;
        const short* Kh = Kbf + ((size_t)(b*HEADS + h))*TSEQ*DH;
        #pragma unroll
        for (int i = 0; i < 4; i++){
            int c = tid + i*256;
            int row = c >> 4, c8 = c & 15;
            *(bf16x8*)(&Q_lds[row][c8*8]) =
                *(const bf16x8*)(Qh + (size_t)(q0+row)*DH + c8*8);
            *(bf16x8*)(&K_lds2[row][c8*8]) =
                *(const bf16x8*)(Kh + (size_t)(k0+row)*DH + c8*8);
        }
        __syncthreads();
        float mh[4], rlh[4];
        #pragma unroll
        for (int r = 0; r < 4; r++){
            int t = q0 + w*16 + lg*4 + r;
            mh[r]  = Mb[((size_t)(b*HEADS + h))*TSEQ + t];
            rlh[r] = Lb[((size_t)(b*HEADS + h))*TSEQ + t];
        }
        f32x4 sacc[4];
        #pragma unroll
        for (int nf = 0; nf < 4; nf++) sacc[nf] = fzero;
        #pragma unroll
        for (int ks = 0; ks < 4; ks++){
            bf16x8 a = *(const bf16x8*)(&Q_lds[w*16 + lr][ks*32 + lg*8]);
            #pragma unroll
            for (int nf = 0; nf < 4; nf++){
                bf16x8 bb = *(const bf16x8*)(&K_lds2[nf*16 + lr][ks*32 + lg*8]);
                sacc[nf] = __builtin_amdgcn_mfma_f32_16x16x32_bf16(a, bb, sacc[nf], 0,0,0);
            }
        }
        #pragma unroll
        for (int nf = 0; nf < 4; nf++)
            #pragma unroll
            for (int r = 0; r < 4; r++){
                int qg = q0 + w*16 + lg*4 + r;
                int sg = k0 + nf*16 + lr;
                float v = (sg <= qg) ? __expf(sacc[nf][r] - mh[r]) * rlh[r] : 0.f;
                wacc[nf][r] += v;
            }
        __syncthreads();
    }
    #pragma unroll
    for (int nf = 0; nf < 4; nf++)
        #pragma unroll
        for (int r = 0; r < 4; r++){
            int qg = q0 + w*16 + lg*4 + r;
            int sg = k0 + nf*16 + lr;
            attn[((size_t)b*TSEQ + qg)*TSEQ + sg] = wacc[nf][r] * 0.125f;
        }
}

// ---------------------------------------------------------------------------
// out = Abar[8192,128] @ Wo  (WoT is [1024,128]).  128x128 tile, K=128.
// ---------------------------------------------------------------------------
__global__ __launch_bounds__(256) void gemm_out_kernel(
    const short* __restrict__ Abar, const short* __restrict__ WoT,
    float* __restrict__ out)
{
    __shared__ short A_lds[128][40];
    __shared__ short B_lds[128][40];
    const int tid = threadIdx.x;
    const int w = tid >> 6, l = tid & 63, lg = l >> 4, lr = l & 15;
    const int wm = w >> 1, wn = w & 1;
    const int n0 = blockIdx.x * 128;
    const int m0 = blockIdx.y * 128;
    const f32x4 fzero = {0.f, 0.f, 0.f, 0.f};
    f32x4 acc[4][4];
    #pragma unroll
    for (int i = 0; i < 4; i++)
        #pragma unroll
        for (int j = 0; j < 4; j++) acc[i][j] = fzero;

    for (int k0 = 0; k0 < DH; k0 += 32){
        #pragma unroll
        for (int i = 0; i < 2; i++){
            int c = tid + i*256;
            int row = c >> 2, c8 = c & 3;
            *(bf16x8*)(&A_lds[row][c8*8]) =
                *(const bf16x8*)(Abar + (size_t)(m0+row)*DH + k0 + c8*8);
            *(bf16x8*)(&B_lds[row][c8*8]) =
                *(const bf16x8*)(WoT + (size_t)(n0+row)*DH + k0 + c8*8);
        }
        __syncthreads();
        bf16x8 af[4], bfr[4];
        #pragma unroll
        for (int mf = 0; mf < 4; mf++)
            af[mf] = *(const bf16x8*)(&A_lds[wm*64 + mf*16 + lr][lg*8]);
        #pragma unroll
        for (int nf = 0; nf < 4; nf++)
            bfr[nf] = *(const bf16x8*)(&B_lds[wn*64 + nf*16 + lr][lg*8]);
        #pragma unroll
        for (int mf = 0; mf < 4; mf++)
            #pragma unroll
            for (int nf = 0; nf < 4; nf++)
                acc[mf][nf] = __builtin_amdgcn_mfma_f32_16x16x32_bf16(
                    af[mf], bfr[nf], acc[mf][nf], 0, 0, 0);
        __syncthreads();
    }
    #pragma unroll
    for (int mf = 0; mf < 4; mf++)
        #pragma unroll
        for (int nf = 0; nf < 4; nf++)
            #pragma unroll
            for (int r = 0; r < 4; r++){
                int gr = m0 + wm*64 + mf*16 + lg*4 + r;
                int gc = n0 + wn*64 + nf*16 + lr;
                out[(size_t)gr*UNITS + gc] = acc[mf][nf][r];
            }
}

// ---------------------------------------------------------------------------
extern "C" void kernel_launch(void* const* d_in, const int* in_sizes, int n_in,
                              void* d_out, int out_size, void* d_ws, size_t ws_size,
                              hipStream_t stream)
{
    const float* x  = (const float*)d_in[0];
    const float* Wq = (const float*)d_in[1];
    const float* Wk = (const float*)d_in[2];
    const float* Wv = (const float*)d_in[3];
    const float* Wo = (const float*)d_in[4];
    float* out  = (float*)d_out;
    float* attn = out + (size_t)MROWS*UNITS;   // 8,388,608 floats in

    char* ws = (char*)d_ws;
    // layout (bytes):
    short* Xbf = (short*)(ws);                       // 16,777,216
    short* WT  = (short*)(ws + 16777216);            //  4,456,448
    short* Qbf = (short*)(ws + 21233664);            // 16,777,216
    short* Kbf = (short*)(ws + 38010880);            // 16,777,216
    short* Vt  = (short*)(ws + 54788096);            //  2,097,152
    float* Mb  = (float*)(ws + 56885248);            //    262,144
    float* Lb  = (float*)(ws + 57147392);            //    262,144
    short* WoT = (short*)(ws + 57409536);            //    262,144  (end ~57.7MB)
    short* Obuf = Xbf;   // alias: Xbf dead after gemm_qkv
    short* Abar = WT;    // alias: WT dead after gemm_qkv

    // zero the strictly-upper-triangular part of attn (and everything else;
    // causal tiles get overwritten by attn_kernel)
    hipMemsetAsync(attn, 0, (size_t)MROWS*TSEQ*sizeof(float), stream);

    pack_kernel<<<4096, 256, 0, stream>>>(x, Wq, Wk, Wv, Wo, Xbf, WT, WoT);
    gemm_qkv_kernel<<<dim3(NCAT/128, MROWS/128), 256, 0, stream>>>(Xbf, WT, Qbf, Kbf, Vt);
    flash_o_kernel<<<dim3(TSEQ/64, BATCH*HEADS), 256, 0, stream>>>(Qbf, Kbf, Vt, Obuf, Mb, Lb);
    mean_kernel<<<(MROWS*DH)/256, 256, 0, stream>>>(Obuf, Abar);
    attn_kernel<<<dim3((TSEQ/64)*(TSEQ/64 + 1)/2, BATCH), 256, 0, stream>>>(Qbf, Kbf, Mb, Lb, attn);
    gemm_out_kernel<<<dim3(UNITS/128, MROWS/128), 256, 0, stream>>>(Abar, WoT, out);
}